// Round 1
// baseline (665.624 us; speedup 1.0000x reference)
//
#include <hip/hip_runtime.h>
#include <hip/hip_bf16.h>

// GCN 2-layer: x[N,128] @ W1 -> scatter(norm) -> +b1,relu -> @ W2 -> scatter(norm) -> +b2
// Round 1: push-scatter with native fp32 atomics.

__global__ __launch_bounds__(256) void k_deg_init(float* __restrict__ deg, int n) {
    int i = blockIdx.x * blockDim.x + threadIdx.x;
    if (i < n) deg[i] = 1.0f;  // self-loop weight
}

__global__ __launch_bounds__(256) void k_deg_acc(const int* __restrict__ dst,
                                                 const float* __restrict__ w,
                                                 float* __restrict__ deg, int E) {
    int e = blockIdx.x * blockDim.x + threadIdx.x;
    if (e < E) unsafeAtomicAdd(&deg[dst[e]], w[e]);
}

__global__ __launch_bounds__(256) void k_dinv(float* __restrict__ deg, int n) {
    int i = blockIdx.x * blockDim.x + threadIdx.x;
    if (i < n) {
        float d = deg[i];
        deg[i] = (d > 0.f) ? rsqrtf(d) : 0.f;  // in-place: deg -> dinv
    }
}

__global__ __launch_bounds__(256) void k_norm(const int* __restrict__ src,
                                              const int* __restrict__ dst,
                                              const float* __restrict__ w,
                                              const float* __restrict__ dinv,
                                              float* __restrict__ norm, int E) {
    int e = blockIdx.x * blockDim.x + threadIdx.x;
    if (e < E) norm[e] = dinv[src[e]] * w[e] * dinv[dst[e]];
}

// GEMM1: h = x @ W1  (N x 128 @ 128 x 64), also writes agg init = h * dinv^2 (self-loop).
// Tile: 64 rows x 64 cols per block, 256 threads, thread computes 4x4, BK=16.
__global__ __launch_bounds__(256) void k_gemm1(const float* __restrict__ x,
                                               const float* __restrict__ W,
                                               const float* __restrict__ dinv,
                                               float* __restrict__ h,
                                               float* __restrict__ agg, int n) {
    constexpr int TM = 64, TN = 64, BK = 16;
    __shared__ float xs[BK][TM + 4];  // stride 68 floats: 16B-aligned rows, low conflicts
    __shared__ float ws[BK][TN + 4];
    const int tid = threadIdx.x;
    const int tx = tid & 15, ty = tid >> 4;
    const int r0 = blockIdx.x * TM;

    float acc[4][4] = {};
    for (int k0 = 0; k0 < 128; k0 += BK) {
        {   // stage x tile (transposed to [k][row])
            int kk = tid & 15;
            int row = tid >> 4;
            #pragma unroll
            for (int p = 0; p < 4; ++p) {
                int rr = row + p * 16;
                float v = (r0 + rr < n) ? x[(size_t)(r0 + rr) * 128 + k0 + kk] : 0.f;
                xs[kk][rr] = v;
            }
        }
        {   // stage W tile [k][c]
            int c = tid & 63;
            int kb = tid >> 6;
            #pragma unroll
            for (int p = 0; p < 4; ++p) {
                int kk = kb + p * 4;
                ws[kk][c] = W[(size_t)(k0 + kk) * 64 + c];
            }
        }
        __syncthreads();
        #pragma unroll
        for (int kk = 0; kk < BK; ++kk) {
            const float4 av = *reinterpret_cast<const float4*>(&xs[kk][ty * 4]);
            const float4 bv = *reinterpret_cast<const float4*>(&ws[kk][tx * 4]);
            const float a[4] = {av.x, av.y, av.z, av.w};
            const float b[4] = {bv.x, bv.y, bv.z, bv.w};
            #pragma unroll
            for (int i = 0; i < 4; ++i)
                #pragma unroll
                for (int j = 0; j < 4; ++j)
                    acc[i][j] = fmaf(a[i], b[j], acc[i][j]);
        }
        __syncthreads();
    }
    #pragma unroll
    for (int i = 0; i < 4; ++i) {
        int r = r0 + ty * 4 + i;
        if (r < n) {
            float di = dinv[r];
            float sc = di * di;  // self-loop coefficient 1/deg
            #pragma unroll
            for (int j = 0; j < 4; ++j) {
                float v = acc[i][j];
                h[(size_t)r * 64 + tx * 4 + j] = v;
                agg[(size_t)r * 64 + tx * 4 + j] = v * sc;
            }
        }
    }
}

// Scatter layer 1: one wave per edge, lane = channel (64 ch).
__global__ __launch_bounds__(256) void k_scatter64(const int* __restrict__ src,
                                                   const int* __restrict__ dst,
                                                   const float* __restrict__ norm,
                                                   const float* __restrict__ h,
                                                   float* __restrict__ agg, int E) {
    int gid = blockIdx.x * blockDim.x + threadIdx.x;
    int e = gid >> 6;
    int lane = gid & 63;
    if (e >= E) return;
    int s = src[e], d = dst[e];
    float nm = norm[e];
    float v = h[(size_t)s * 64 + lane] * nm;
    unsafeAtomicAdd(&agg[(size_t)d * 64 + lane], v);
}

// GEMM2: reads agg1, applies +b1 and relu inline, computes @ W2 (64x32).
// Writes h2 (for scatter) and out init = h2*dinv^2 + b2.
// One wave per 2 rows: lane = (subrow<<5) | col.
__global__ __launch_bounds__(256) void k_gemm2(const float* __restrict__ agg1,
                                               const float* __restrict__ W2,
                                               const float* __restrict__ b1,
                                               const float* __restrict__ b2,
                                               const float* __restrict__ dinv,
                                               float* __restrict__ h2,
                                               float* __restrict__ out, int n) {
    __shared__ float ws[64][33];   // W2 padded
    __shared__ float xs[4][128];   // per-wave: 2 rows x 64 (relu'd inputs)
    const int tid = threadIdx.x;
    for (int i = tid; i < 64 * 32; i += 256)
        ws[i >> 5][i & 31] = W2[i];
    __syncthreads();

    const int wave = tid >> 6, lane = tid & 63;
    const int r0 = (blockIdx.x * 4 + wave) * 2;  // first row of this wave's pair
    if (r0 >= n) return;

    // stage relu(agg1 + b1) for the 2 rows (contiguous 128 floats)
    {
        float bv = b1[lane];
        float v0 = agg1[(size_t)r0 * 64 + lane];
        xs[wave][lane] = fmaxf(v0 + bv, 0.f);
        if (r0 + 1 < n) {
            float v1 = agg1[(size_t)r0 * 64 + 64 + lane];
            xs[wave][64 + lane] = fmaxf(v1 + bv, 0.f);
        }
    }
    const int s = lane >> 5;      // subrow 0/1
    const int c = lane & 31;      // output channel
    const int r = r0 + s;
    if (r >= n) return;
    float acc = 0.f;
    #pragma unroll
    for (int k = 0; k < 64; ++k)
        acc = fmaf(xs[wave][s * 64 + k], ws[k][c], acc);
    h2[(size_t)r * 32 + c] = acc;
    float di = dinv[r];
    out[(size_t)r * 32 + c] = acc * di * di + b2[c];
}

// Scatter layer 2: one wave per 2 edges, 32 ch each.
__global__ __launch_bounds__(256) void k_scatter32(const int* __restrict__ src,
                                                   const int* __restrict__ dst,
                                                   const float* __restrict__ norm,
                                                   const float* __restrict__ h,
                                                   float* __restrict__ out, int E) {
    int gid = blockIdx.x * blockDim.x + threadIdx.x;
    int e = gid >> 5;
    int lane = gid & 31;
    if (e >= E) return;
    int s = src[e], d = dst[e];
    float nm = norm[e];
    float v = h[(size_t)s * 32 + lane] * nm;
    unsafeAtomicAdd(&out[(size_t)d * 32 + lane], v);
}

extern "C" void kernel_launch(void* const* d_in, const int* in_sizes, int n_in,
                              void* d_out, int out_size, void* d_ws, size_t ws_size,
                              hipStream_t stream) {
    const float* x  = (const float*)d_in[0];   // [n,128]
    const int*   ei = (const int*)d_in[1];     // [2,E]
    const float* ew = (const float*)d_in[2];   // [E]
    const float* W1 = (const float*)d_in[3];   // [128,64]
    const float* b1 = (const float*)d_in[4];   // [64]
    const float* W2 = (const float*)d_in[5];   // [64,32]
    const float* b2 = (const float*)d_in[6];   // [32]
    float* out = (float*)d_out;

    const int n = in_sizes[0] / 128;
    const int E = in_sizes[2];
    const int* src = ei;
    const int* dst = ei + E;

    // workspace layout (floats): dinv[n] | norm[E] | h1[n*64] | agg1[n*64]
    float* dinv = (float*)d_ws;
    float* norm = dinv + n;
    float* h1   = norm + E;
    float* agg1 = h1 + (size_t)n * 64;
    float* h2   = h1;  // reuse h1 buffer after scatter1 (n*32 <= n*64)

    k_deg_init<<<(n + 255) / 256, 256, 0, stream>>>(dinv, n);
    k_deg_acc<<<(E + 255) / 256, 256, 0, stream>>>(dst, ew, dinv, E);
    k_dinv<<<(n + 255) / 256, 256, 0, stream>>>(dinv, n);
    k_norm<<<(E + 255) / 256, 256, 0, stream>>>(src, dst, ew, dinv, norm, E);

    k_gemm1<<<(n + 63) / 64, 256, 0, stream>>>(x, W1, dinv, h1, agg1, n);
    k_scatter64<<<(int)(((size_t)E * 64 + 255) / 256), 256, 0, stream>>>(src, dst, norm, h1, agg1, E);

    k_gemm2<<<(n + 7) / 8, 256, 0, stream>>>(agg1, W2, b1, b2, dinv, h2, out, n);
    k_scatter32<<<(int)(((size_t)E * 32 + 255) / 256), 256, 0, stream>>>(src, dst, norm, h2, out, E);
}

// Round 2
// 665.255 us; speedup vs baseline: 1.0006x; 1.0006x over previous
//
#include <hip/hip_runtime.h>
#include <hip/hip_bf16.h>

// GCN 2-layer, pull-based (CSR by dst, built on device each call).
// Pipeline:
//   k_init:   deg=1 (self loop), count=0
//   k_hist:   deg[dst]+=w, count[dst]++          (atomics, small)
//   k_dinv:   dinv = rsqrt(deg)                  (in place)
//   k_scan:   row_start = exclusive_scan(count); cursor = copy
//   k_fill:   pack[pos] = (src, norm) per edge   (cursor atomics)
//   k_gemm1:  h1 = x @ W1                        (tiled, 4x4/thread)
//   k_layer1: per node: acc = pull(h1)*norm + self; r=relu(acc+b1);
//             h2 = r @ W2 via shfl broadcast     (fused, no LDS)
//   k_layer2: out = pull(h2)*norm + self + b2

__global__ __launch_bounds__(256) void k_init(float* __restrict__ deg,
                                              int* __restrict__ count, int n) {
    int i = blockIdx.x * blockDim.x + threadIdx.x;
    if (i < n) { deg[i] = 1.0f; count[i] = 0; }
}

__global__ __launch_bounds__(256) void k_hist(const int* __restrict__ dst,
                                              const float* __restrict__ w,
                                              float* __restrict__ deg,
                                              int* __restrict__ count, int E) {
    int e = blockIdx.x * blockDim.x + threadIdx.x;
    if (e < E) {
        int d = dst[e];
        unsafeAtomicAdd(&deg[d], w[e]);
        atomicAdd(&count[d], 1);
    }
}

__global__ __launch_bounds__(256) void k_dinv(float* __restrict__ deg, int n) {
    int i = blockIdx.x * blockDim.x + threadIdx.x;
    if (i < n) {
        float d = deg[i];
        deg[i] = (d > 0.f) ? rsqrtf(d) : 0.f;
    }
}

// Single-block exclusive scan of count[n] -> row_start, cursor (copy).
__global__ __launch_bounds__(1024) void k_scan(const int* __restrict__ count,
                                               int* __restrict__ rowst,
                                               int* __restrict__ cursor, int n) {
    __shared__ int lds[1024];
    const int t = threadIdx.x;
    const int chunk = (n + 1023) >> 10;
    const int lo = t * chunk, hi = min(lo + chunk, n);
    int s = 0;
    for (int i = lo; i < hi; ++i) s += count[i];
    lds[t] = s;
    __syncthreads();
    for (int off = 1; off < 1024; off <<= 1) {
        int u = (t >= off) ? lds[t - off] : 0;
        __syncthreads();
        lds[t] += u;
        __syncthreads();
    }
    int run = (t > 0) ? lds[t - 1] : 0;   // exclusive base for this chunk
    for (int i = lo; i < hi; ++i) {
        rowst[i] = run;
        cursor[i] = run;
        run += count[i];
    }
}

__global__ __launch_bounds__(256) void k_fill(const int* __restrict__ src,
                                              const int* __restrict__ dst,
                                              const float* __restrict__ w,
                                              const float* __restrict__ dinv,
                                              int* __restrict__ cursor,
                                              int2* __restrict__ pack, int E) {
    int e = blockIdx.x * blockDim.x + threadIdx.x;
    if (e < E) {
        int s = src[e], d = dst[e];
        float nm = dinv[s] * w[e] * dinv[d];
        int pos = atomicAdd(&cursor[d], 1);
        pack[pos] = make_int2(s, __float_as_int(nm));
    }
}

// GEMM1: h1 = x @ W1  (n x 128 @ 128 x 64). 64x64 tile, 256 thr, 4x4/thread.
__global__ __launch_bounds__(256) void k_gemm1(const float* __restrict__ x,
                                               const float* __restrict__ W,
                                               float* __restrict__ h, int n) {
    constexpr int TM = 64, BK = 16;
    __shared__ float xs[BK][TM + 4];
    __shared__ float ws[BK][64 + 4];
    const int tid = threadIdx.x;
    const int tx = tid & 15, ty = tid >> 4;
    const int r0 = blockIdx.x * TM;

    float acc[4][4] = {};
    for (int k0 = 0; k0 < 128; k0 += BK) {
        {
            int kk = tid & 15;
            int row = tid >> 4;
            #pragma unroll
            for (int p = 0; p < 4; ++p) {
                int rr = row + p * 16;
                xs[kk][rr] = (r0 + rr < n) ? x[(size_t)(r0 + rr) * 128 + k0 + kk] : 0.f;
            }
        }
        {
            int c = tid & 63;
            int kb = tid >> 6;
            #pragma unroll
            for (int p = 0; p < 4; ++p) {
                int kk = kb + p * 4;
                ws[kk][c] = W[(size_t)(k0 + kk) * 64 + c];
            }
        }
        __syncthreads();
        #pragma unroll
        for (int kk = 0; kk < BK; ++kk) {
            const float4 av = *reinterpret_cast<const float4*>(&xs[kk][ty * 4]);
            const float4 bv = *reinterpret_cast<const float4*>(&ws[kk][tx * 4]);
            const float a[4] = {av.x, av.y, av.z, av.w};
            const float b[4] = {bv.x, bv.y, bv.z, bv.w};
            #pragma unroll
            for (int i = 0; i < 4; ++i)
                #pragma unroll
                for (int j = 0; j < 4; ++j)
                    acc[i][j] = fmaf(a[i], b[j], acc[i][j]);
        }
        __syncthreads();
    }
    #pragma unroll
    for (int i = 0; i < 4; ++i) {
        int r = r0 + ty * 4 + i;
        if (r < n)
            #pragma unroll
            for (int j = 0; j < 4; ++j)
                h[(size_t)r * 64 + tx * 4 + j] = acc[i][j];
    }
}

// Fused: pull-aggregate layer1 (64 ch) + bias + relu + (64->32) @ W2 -> h2.
// One wave per node (persistent grid-stride). W2 column cached in 32 VGPRs.
// Projection via __shfl broadcast: no LDS, no barriers.
__global__ __launch_bounds__(256) void k_layer1(const float* __restrict__ h1,
                                                const int2* __restrict__ pack,
                                                const int* __restrict__ rowst,
                                                const int* __restrict__ count,
                                                const float* __restrict__ dinv,
                                                const float* __restrict__ b1,
                                                const float* __restrict__ W2,
                                                float* __restrict__ h2, int n) {
    const int lane = threadIdx.x & 63;
    const int wid = (blockIdx.x * blockDim.x + threadIdx.x) >> 6;
    const int nwaves = (gridDim.x * blockDim.x) >> 6;
    const int half = lane >> 5, c = lane & 31;

    float w[32];
    #pragma unroll
    for (int k = 0; k < 32; ++k)
        w[k] = W2[(half * 32 + k) * 32 + c];
    const float bb = b1[lane];

    for (int v = wid; v < n; v += nwaves) {
        const float di = dinv[v];
        float acc = h1[v * 64 + lane] * di * di;   // self loop: norm = 1/deg
        const int start = rowst[v], cnt = count[v];
        const int2* pk = pack + start;
        int j = 0;
        for (; j + 4 <= cnt; j += 4) {
            int2 p0 = pk[j], p1 = pk[j + 1], p2 = pk[j + 2], p3 = pk[j + 3];
            float a0 = h1[p0.x * 64 + lane];
            float a1 = h1[p1.x * 64 + lane];
            float a2 = h1[p2.x * 64 + lane];
            float a3 = h1[p3.x * 64 + lane];
            acc = fmaf(a0, __int_as_float(p0.y), acc);
            acc = fmaf(a1, __int_as_float(p1.y), acc);
            acc = fmaf(a2, __int_as_float(p2.y), acc);
            acc = fmaf(a3, __int_as_float(p3.y), acc);
        }
        for (; j < cnt; ++j) {
            int2 p = pk[j];
            acc = fmaf(h1[p.x * 64 + lane], __int_as_float(p.y), acc);
        }
        const float r = fmaxf(acc + bb, 0.f);      // relu (leaky_relu = id on >=0)

        // 64->32 projection: lane (half,c) accumulates k in [half*32, half*32+32)
        float o = 0.f;
        #pragma unroll
        for (int k = 0; k < 32; ++k)
            o = fmaf(__shfl(r, half * 32 + k, 64), w[k], o);
        o += __shfl_xor(o, 32, 64);
        if (half == 0) h2[v * 32 + c] = o;
    }
}

// Layer2 pull: out = pull(h2) + self + b2. Half-wave per node-half: lanes split
// neighbors by parity; 32 ch each.
__global__ __launch_bounds__(256) void k_layer2(const float* __restrict__ h2,
                                                const int2* __restrict__ pack,
                                                const int* __restrict__ rowst,
                                                const int* __restrict__ count,
                                                const float* __restrict__ dinv,
                                                const float* __restrict__ b2,
                                                float* __restrict__ out, int n) {
    const int lane = threadIdx.x & 63;
    const int wid = (blockIdx.x * blockDim.x + threadIdx.x) >> 6;
    const int nwaves = (gridDim.x * blockDim.x) >> 6;
    const int half = lane >> 5, c = lane & 31;
    const float bb = b2[c];

    for (int v = wid; v < n; v += nwaves) {
        const float di = dinv[v];
        float acc = (half == 0) ? h2[v * 32 + c] * di * di : 0.f;
        const int start = rowst[v], cnt = count[v];
        const int2* pk = pack + start;
        int j = half;
        for (; j + 2 < cnt; j += 4) {
            int2 p0 = pk[j], p1 = pk[j + 2];
            float a0 = h2[p0.x * 32 + c];
            float a1 = h2[p1.x * 32 + c];
            acc = fmaf(a0, __int_as_float(p0.y), acc);
            acc = fmaf(a1, __int_as_float(p1.y), acc);
        }
        for (; j < cnt; j += 2) {
            int2 p = pk[j];
            acc = fmaf(h2[p.x * 32 + c], __int_as_float(p.y), acc);
        }
        acc += __shfl_xor(acc, 32, 64);
        if (half == 0) out[v * 32 + c] = acc + bb;
    }
}

extern "C" void kernel_launch(void* const* d_in, const int* in_sizes, int n_in,
                              void* d_out, int out_size, void* d_ws, size_t ws_size,
                              hipStream_t stream) {
    const float* x  = (const float*)d_in[0];   // [n,128]
    const int*   ei = (const int*)d_in[1];     // [2,E]
    const float* ew = (const float*)d_in[2];   // [E]
    const float* W1 = (const float*)d_in[3];   // [128,64]
    const float* b1 = (const float*)d_in[4];   // [64]
    const float* W2 = (const float*)d_in[5];   // [64,32]
    const float* b2 = (const float*)d_in[6];   // [32]
    float* out = (float*)d_out;

    const int n = in_sizes[0] / 128;
    const int E = in_sizes[2];
    const int* src = ei;
    const int* dst = ei + E;

    // workspace: deg/dinv[n] | count[n] | rowst[n] | cursor[n] | pack[E]int2 | h1[n*64] | h2[n*32]
    float* deg    = (float*)d_ws;
    int*   count  = (int*)(deg + n);
    int*   rowst  = count + n;
    int*   cursor = rowst + n;
    int2*  pack   = (int2*)(cursor + n);
    float* h1     = (float*)(pack + E);
    float* h2     = h1 + (size_t)n * 64;

    k_init<<<(n + 255) / 256, 256, 0, stream>>>(deg, count, n);
    k_hist<<<(E + 255) / 256, 256, 0, stream>>>(dst, ew, deg, count, E);
    k_dinv<<<(n + 255) / 256, 256, 0, stream>>>(deg, n);
    k_scan<<<1, 1024, 0, stream>>>(count, rowst, cursor, n);
    k_fill<<<(E + 255) / 256, 256, 0, stream>>>(src, dst, ew, deg, cursor, pack, E);

    k_gemm1<<<(n + 63) / 64, 256, 0, stream>>>(x, W1, h1, n);
    k_layer1<<<2048, 256, 0, stream>>>(h1, pack, rowst, count, deg, b1, W2, h2, n);
    k_layer2<<<2048, 256, 0, stream>>>(h2, pack, rowst, count, deg, b2, out, n);
}

// Round 3
// 452.404 us; speedup vs baseline: 1.4713x; 1.4705x over previous
//
#include <hip/hip_runtime.h>
#include <hip/hip_bf16.h>

// GCN 2-layer, pull-based (CSR by dst, built on device each call).
// Round 3: replace single-block scan (228us, 0.15% occupancy) with
// 3-kernel hierarchical scan. Everything else unchanged.

constexpr int SCAN_CHUNK = 1024;   // elements per block (256 thr x 4)

__global__ __launch_bounds__(256) void k_init(float* __restrict__ deg,
                                              int* __restrict__ count, int n) {
    int i = blockIdx.x * blockDim.x + threadIdx.x;
    if (i < n) { deg[i] = 1.0f; count[i] = 0; }
}

__global__ __launch_bounds__(256) void k_hist(const int* __restrict__ dst,
                                              const float* __restrict__ w,
                                              float* __restrict__ deg,
                                              int* __restrict__ count, int E) {
    int e = blockIdx.x * blockDim.x + threadIdx.x;
    if (e < E) {
        int d = dst[e];
        unsafeAtomicAdd(&deg[d], w[e]);
        atomicAdd(&count[d], 1);
    }
}

__global__ __launch_bounds__(256) void k_dinv(float* __restrict__ deg, int n) {
    int i = blockIdx.x * blockDim.x + threadIdx.x;
    if (i < n) {
        float d = deg[i];
        deg[i] = (d > 0.f) ? rsqrtf(d) : 0.f;
    }
}

// scan A: per-block sums of count (chunk = 1024)
__global__ __launch_bounds__(256) void k_scan_a(const int* __restrict__ count,
                                                int* __restrict__ bsum, int n) {
    __shared__ int wtot[4];
    const int t = threadIdx.x;
    const int base = blockIdx.x * SCAN_CHUNK + t * 4;
    int s = 0;
    #pragma unroll
    for (int k = 0; k < 4; ++k) {
        int i = base + k;
        if (i < n) s += count[i];
    }
    #pragma unroll
    for (int off = 1; off < 64; off <<= 1) s += __shfl_xor(s, off, 64);
    if ((t & 63) == 0) wtot[t >> 6] = s;
    __syncthreads();
    if (t == 0) bsum[blockIdx.x] = wtot[0] + wtot[1] + wtot[2] + wtot[3];
}

// scan B: exclusive scan of bsum[P] in place, single block (P <= 1024)
__global__ __launch_bounds__(1024) void k_scan_b(int* __restrict__ bsum, int P) {
    __shared__ int wtot[16];
    const int t = threadIdx.x;
    const int lane = t & 63, wv = t >> 6;
    int v = (t < P) ? bsum[t] : 0;
    int inc = v;
    #pragma unroll
    for (int off = 1; off < 64; off <<= 1) {
        int u = __shfl_up(inc, off, 64);
        if (lane >= off) inc += u;
    }
    if (lane == 63) wtot[wv] = inc;
    __syncthreads();
    int wbase = 0;
    for (int w = 0; w < wv; ++w) wbase += wtot[w];
    if (t < P) bsum[t] = wbase + inc - v;   // exclusive
}

// scan C: per-block exclusive scan + block base -> rowst, cursor
__global__ __launch_bounds__(256) void k_scan_c(const int* __restrict__ count,
                                                const int* __restrict__ bsum,
                                                int* __restrict__ rowst,
                                                int* __restrict__ cursor, int n) {
    __shared__ int wtot[4];
    const int t = threadIdx.x;
    const int lane = t & 63, wv = t >> 6;
    const int base = blockIdx.x * SCAN_CHUNK + t * 4;
    int c[4];
    int s = 0;
    #pragma unroll
    for (int k = 0; k < 4; ++k) {
        int i = base + k;
        c[k] = (i < n) ? count[i] : 0;
        s += c[k];
    }
    int inc = s;
    #pragma unroll
    for (int off = 1; off < 64; off <<= 1) {
        int u = __shfl_up(inc, off, 64);
        if (lane >= off) inc += u;
    }
    if (lane == 63) wtot[wv] = inc;
    __syncthreads();
    int run = bsum[blockIdx.x] + (inc - s);
    for (int w = 0; w < wv; ++w) run += wtot[w];
    #pragma unroll
    for (int k = 0; k < 4; ++k) {
        int i = base + k;
        if (i < n) { rowst[i] = run; cursor[i] = run; }
        run += c[k];
    }
}

__global__ __launch_bounds__(256) void k_fill(const int* __restrict__ src,
                                              const int* __restrict__ dst,
                                              const float* __restrict__ w,
                                              const float* __restrict__ dinv,
                                              int* __restrict__ cursor,
                                              int2* __restrict__ pack, int E) {
    int e = blockIdx.x * blockDim.x + threadIdx.x;
    if (e < E) {
        int s = src[e], d = dst[e];
        float nm = dinv[s] * w[e] * dinv[d];
        int pos = atomicAdd(&cursor[d], 1);
        pack[pos] = make_int2(s, __float_as_int(nm));
    }
}

// GEMM1: h1 = x @ W1  (n x 128 @ 128 x 64). 64x64 tile, 256 thr, 4x4/thread.
__global__ __launch_bounds__(256) void k_gemm1(const float* __restrict__ x,
                                               const float* __restrict__ W,
                                               float* __restrict__ h, int n) {
    constexpr int TM = 64, BK = 16;
    __shared__ float xs[BK][TM + 4];
    __shared__ float ws[BK][64 + 4];
    const int tid = threadIdx.x;
    const int tx = tid & 15, ty = tid >> 4;
    const int r0 = blockIdx.x * TM;

    float acc[4][4] = {};
    for (int k0 = 0; k0 < 128; k0 += BK) {
        {
            int kk = tid & 15;
            int row = tid >> 4;
            #pragma unroll
            for (int p = 0; p < 4; ++p) {
                int rr = row + p * 16;
                xs[kk][rr] = (r0 + rr < n) ? x[(size_t)(r0 + rr) * 128 + k0 + kk] : 0.f;
            }
        }
        {
            int c = tid & 63;
            int kb = tid >> 6;
            #pragma unroll
            for (int p = 0; p < 4; ++p) {
                int kk = kb + p * 4;
                ws[kk][c] = W[(size_t)(k0 + kk) * 64 + c];
            }
        }
        __syncthreads();
        #pragma unroll
        for (int kk = 0; kk < BK; ++kk) {
            const float4 av = *reinterpret_cast<const float4*>(&xs[kk][ty * 4]);
            const float4 bv = *reinterpret_cast<const float4*>(&ws[kk][tx * 4]);
            const float a[4] = {av.x, av.y, av.z, av.w};
            const float b[4] = {bv.x, bv.y, bv.z, bv.w};
            #pragma unroll
            for (int i = 0; i < 4; ++i)
                #pragma unroll
                for (int j = 0; j < 4; ++j)
                    acc[i][j] = fmaf(a[i], b[j], acc[i][j]);
        }
        __syncthreads();
    }
    #pragma unroll
    for (int i = 0; i < 4; ++i) {
        int r = r0 + ty * 4 + i;
        if (r < n)
            #pragma unroll
            for (int j = 0; j < 4; ++j)
                h[(size_t)r * 64 + tx * 4 + j] = acc[i][j];
    }
}

// Fused: pull-aggregate layer1 (64 ch) + bias + relu + (64->32) @ W2 -> h2.
__global__ __launch_bounds__(256) void k_layer1(const float* __restrict__ h1,
                                                const int2* __restrict__ pack,
                                                const int* __restrict__ rowst,
                                                const int* __restrict__ count,
                                                const float* __restrict__ dinv,
                                                const float* __restrict__ b1,
                                                const float* __restrict__ W2,
                                                float* __restrict__ h2, int n) {
    const int lane = threadIdx.x & 63;
    const int wid = (blockIdx.x * blockDim.x + threadIdx.x) >> 6;
    const int nwaves = (gridDim.x * blockDim.x) >> 6;
    const int half = lane >> 5, c = lane & 31;

    float w[32];
    #pragma unroll
    for (int k = 0; k < 32; ++k)
        w[k] = W2[(half * 32 + k) * 32 + c];
    const float bb = b1[lane];

    for (int v = wid; v < n; v += nwaves) {
        const float di = dinv[v];
        float acc = h1[v * 64 + lane] * di * di;   // self loop: norm = 1/deg
        const int start = rowst[v], cnt = count[v];
        const int2* pk = pack + start;
        int j = 0;
        for (; j + 4 <= cnt; j += 4) {
            int2 p0 = pk[j], p1 = pk[j + 1], p2 = pk[j + 2], p3 = pk[j + 3];
            float a0 = h1[p0.x * 64 + lane];
            float a1 = h1[p1.x * 64 + lane];
            float a2 = h1[p2.x * 64 + lane];
            float a3 = h1[p3.x * 64 + lane];
            acc = fmaf(a0, __int_as_float(p0.y), acc);
            acc = fmaf(a1, __int_as_float(p1.y), acc);
            acc = fmaf(a2, __int_as_float(p2.y), acc);
            acc = fmaf(a3, __int_as_float(p3.y), acc);
        }
        for (; j < cnt; ++j) {
            int2 p = pk[j];
            acc = fmaf(h1[p.x * 64 + lane], __int_as_float(p.y), acc);
        }
        const float r = fmaxf(acc + bb, 0.f);      // relu (leaky_relu = id on >=0)

        float o = 0.f;
        #pragma unroll
        for (int k = 0; k < 32; ++k)
            o = fmaf(__shfl(r, half * 32 + k, 64), w[k], o);
        o += __shfl_xor(o, 32, 64);
        if (half == 0) h2[v * 32 + c] = o;
    }
}

// Layer2 pull: out = pull(h2) + self + b2.
__global__ __launch_bounds__(256) void k_layer2(const float* __restrict__ h2,
                                                const int2* __restrict__ pack,
                                                const int* __restrict__ rowst,
                                                const int* __restrict__ count,
                                                const float* __restrict__ dinv,
                                                const float* __restrict__ b2,
                                                float* __restrict__ out, int n) {
    const int lane = threadIdx.x & 63;
    const int wid = (blockIdx.x * blockDim.x + threadIdx.x) >> 6;
    const int nwaves = (gridDim.x * blockDim.x) >> 6;
    const int half = lane >> 5, c = lane & 31;
    const float bb = b2[c];

    for (int v = wid; v < n; v += nwaves) {
        const float di = dinv[v];
        float acc = (half == 0) ? h2[v * 32 + c] * di * di : 0.f;
        const int start = rowst[v], cnt = count[v];
        const int2* pk = pack + start;
        int j = half;
        for (; j + 2 < cnt; j += 4) {
            int2 p0 = pk[j], p1 = pk[j + 2];
            float a0 = h2[p0.x * 32 + c];
            float a1 = h2[p1.x * 32 + c];
            acc = fmaf(a0, __int_as_float(p0.y), acc);
            acc = fmaf(a1, __int_as_float(p1.y), acc);
        }
        for (; j < cnt; j += 2) {
            int2 p = pk[j];
            acc = fmaf(h2[p.x * 32 + c], __int_as_float(p.y), acc);
        }
        acc += __shfl_xor(acc, 32, 64);
        if (half == 0) out[v * 32 + c] = acc + bb;
    }
}

extern "C" void kernel_launch(void* const* d_in, const int* in_sizes, int n_in,
                              void* d_out, int out_size, void* d_ws, size_t ws_size,
                              hipStream_t stream) {
    const float* x  = (const float*)d_in[0];   // [n,128]
    const int*   ei = (const int*)d_in[1];     // [2,E]
    const float* ew = (const float*)d_in[2];   // [E]
    const float* W1 = (const float*)d_in[3];   // [128,64]
    const float* b1 = (const float*)d_in[4];   // [64]
    const float* W2 = (const float*)d_in[5];   // [64,32]
    const float* b2 = (const float*)d_in[6];   // [32]
    float* out = (float*)d_out;

    const int n = in_sizes[0] / 128;
    const int E = in_sizes[2];
    const int* src = ei;
    const int* dst = ei + E;

    const int P = (n + SCAN_CHUNK - 1) / SCAN_CHUNK;   // scan blocks (98 for n=100k)

    // workspace: deg/dinv[n] | count[n] | rowst[n] | cursor[n] | bsum[P(pad 1024)] |
    //            pack[E]int2 | h1[n*64] | h2[n*32]
    float* deg    = (float*)d_ws;
    int*   count  = (int*)(deg + n);
    int*   rowst  = count + n;
    int*   cursor = rowst + n;
    int*   bsum   = cursor + n;
    int2*  pack   = (int2*)(bsum + 1024);
    float* h1     = (float*)(pack + E);
    float* h2     = h1 + (size_t)n * 64;

    k_init<<<(n + 255) / 256, 256, 0, stream>>>(deg, count, n);
    k_hist<<<(E + 255) / 256, 256, 0, stream>>>(dst, ew, deg, count, E);
    k_dinv<<<(n + 255) / 256, 256, 0, stream>>>(deg, n);
    k_scan_a<<<P, 256, 0, stream>>>(count, bsum, n);
    k_scan_b<<<1, 1024, 0, stream>>>(bsum, P);
    k_scan_c<<<P, 256, 0, stream>>>(count, bsum, rowst, cursor, n);
    k_fill<<<(E + 255) / 256, 256, 0, stream>>>(src, dst, ew, deg, cursor, pack, E);

    k_gemm1<<<(n + 63) / 64, 256, 0, stream>>>(x, W1, h1, n);
    k_layer1<<<2048, 256, 0, stream>>>(h1, pack, rowst, count, deg, b1, W2, h2, n);
    k_layer2<<<2048, 256, 0, stream>>>(h2, pack, rowst, count, deg, b2, out, n);
}

// Round 4
// 365.453 us; speedup vs baseline: 1.8214x; 1.2379x over previous
//
#include <hip/hip_runtime.h>
#include <hip/hip_bf16.h>

// GCN 2-layer, pull-based (CSR by dst, built on device each call).
// Round 4: k_hist's two 32-bit atomics per edge -> one packed 64-bit atomic.
//   packed[d]: high 24 bits = edge count, low 40 bits = sum(w) in 2^-32 fixed point.
//   (max weighted degree ~45 << 256 capacity; resolution beats fp32 accumulation)

constexpr int SCAN_CHUNK = 1024;   // elements per scan block (256 thr x 4)
constexpr unsigned long long CNT_ONE = 1ULL << 40;
constexpr unsigned long long W_MASK  = (1ULL << 40) - 1;

__global__ __launch_bounds__(256) void k_hist(const int* __restrict__ dst,
                                              const float* __restrict__ w,
                                              unsigned long long* __restrict__ packed,
                                              int E) {
    int e = blockIdx.x * blockDim.x + threadIdx.x;
    if (e < E) {
        unsigned long long fixw = (unsigned long long)((double)w[e] * 4294967296.0);
        atomicAdd(&packed[dst[e]], CNT_ONE | fixw);
    }
}

// unpack: dinv = rsqrt(1 + sum_w), count = high bits
__global__ __launch_bounds__(256) void k_dinv(const unsigned long long* __restrict__ packed,
                                              float* __restrict__ dinv,
                                              int* __restrict__ count, int n) {
    int i = blockIdx.x * blockDim.x + threadIdx.x;
    if (i < n) {
        unsigned long long p = packed[i];
        double d = (double)(p & W_MASK) * (1.0 / 4294967296.0) + 1.0;  // +1 self loop
        dinv[i] = rsqrtf((float)d);
        count[i] = (int)(p >> 40);
    }
}

// scan A: per-block sums of count (chunk = 1024)
__global__ __launch_bounds__(256) void k_scan_a(const int* __restrict__ count,
                                                int* __restrict__ bsum, int n) {
    __shared__ int wtot[4];
    const int t = threadIdx.x;
    const int base = blockIdx.x * SCAN_CHUNK + t * 4;
    int s = 0;
    #pragma unroll
    for (int k = 0; k < 4; ++k) {
        int i = base + k;
        if (i < n) s += count[i];
    }
    #pragma unroll
    for (int off = 1; off < 64; off <<= 1) s += __shfl_xor(s, off, 64);
    if ((t & 63) == 0) wtot[t >> 6] = s;
    __syncthreads();
    if (t == 0) bsum[blockIdx.x] = wtot[0] + wtot[1] + wtot[2] + wtot[3];
}

// scan B: exclusive scan of bsum[P] in place, single block (P <= 1024)
__global__ __launch_bounds__(1024) void k_scan_b(int* __restrict__ bsum, int P) {
    __shared__ int wtot[16];
    const int t = threadIdx.x;
    const int lane = t & 63, wv = t >> 6;
    int v = (t < P) ? bsum[t] : 0;
    int inc = v;
    #pragma unroll
    for (int off = 1; off < 64; off <<= 1) {
        int u = __shfl_up(inc, off, 64);
        if (lane >= off) inc += u;
    }
    if (lane == 63) wtot[wv] = inc;
    __syncthreads();
    int wbase = 0;
    for (int w = 0; w < wv; ++w) wbase += wtot[w];
    if (t < P) bsum[t] = wbase + inc - v;   // exclusive
}

// scan C: per-block exclusive scan + block base -> rowst, cursor
__global__ __launch_bounds__(256) void k_scan_c(const int* __restrict__ count,
                                                const int* __restrict__ bsum,
                                                int* __restrict__ rowst,
                                                int* __restrict__ cursor, int n) {
    __shared__ int wtot[4];
    const int t = threadIdx.x;
    const int lane = t & 63, wv = t >> 6;
    const int base = blockIdx.x * SCAN_CHUNK + t * 4;
    int c[4];
    int s = 0;
    #pragma unroll
    for (int k = 0; k < 4; ++k) {
        int i = base + k;
        c[k] = (i < n) ? count[i] : 0;
        s += c[k];
    }
    int inc = s;
    #pragma unroll
    for (int off = 1; off < 64; off <<= 1) {
        int u = __shfl_up(inc, off, 64);
        if (lane >= off) inc += u;
    }
    if (lane == 63) wtot[wv] = inc;
    __syncthreads();
    int run = bsum[blockIdx.x] + (inc - s);
    for (int w = 0; w < wv; ++w) run += wtot[w];
    #pragma unroll
    for (int k = 0; k < 4; ++k) {
        int i = base + k;
        if (i < n) { rowst[i] = run; cursor[i] = run; }
        run += c[k];
    }
}

__global__ __launch_bounds__(256) void k_fill(const int* __restrict__ src,
                                              const int* __restrict__ dst,
                                              const float* __restrict__ w,
                                              const float* __restrict__ dinv,
                                              int* __restrict__ cursor,
                                              int2* __restrict__ pack, int E) {
    int e = blockIdx.x * blockDim.x + threadIdx.x;
    if (e < E) {
        int s = src[e], d = dst[e];
        float nm = dinv[s] * w[e] * dinv[d];
        int pos = atomicAdd(&cursor[d], 1);
        pack[pos] = make_int2(s, __float_as_int(nm));
    }
}

// GEMM1: h1 = x @ W1  (n x 128 @ 128 x 64). 64x64 tile, 256 thr, 4x4/thread.
__global__ __launch_bounds__(256) void k_gemm1(const float* __restrict__ x,
                                               const float* __restrict__ W,
                                               float* __restrict__ h, int n) {
    constexpr int TM = 64, BK = 16;
    __shared__ float xs[BK][TM + 4];
    __shared__ float ws[BK][64 + 4];
    const int tid = threadIdx.x;
    const int tx = tid & 15, ty = tid >> 4;
    const int r0 = blockIdx.x * TM;

    float acc[4][4] = {};
    for (int k0 = 0; k0 < 128; k0 += BK) {
        {
            int kk = tid & 15;
            int row = tid >> 4;
            #pragma unroll
            for (int p = 0; p < 4; ++p) {
                int rr = row + p * 16;
                xs[kk][rr] = (r0 + rr < n) ? x[(size_t)(r0 + rr) * 128 + k0 + kk] : 0.f;
            }
        }
        {
            int c = tid & 63;
            int kb = tid >> 6;
            #pragma unroll
            for (int p = 0; p < 4; ++p) {
                int kk = kb + p * 4;
                ws[kk][c] = W[(size_t)(k0 + kk) * 64 + c];
            }
        }
        __syncthreads();
        #pragma unroll
        for (int kk = 0; kk < BK; ++kk) {
            const float4 av = *reinterpret_cast<const float4*>(&xs[kk][ty * 4]);
            const float4 bv = *reinterpret_cast<const float4*>(&ws[kk][tx * 4]);
            const float a[4] = {av.x, av.y, av.z, av.w};
            const float b[4] = {bv.x, bv.y, bv.z, bv.w};
            #pragma unroll
            for (int i = 0; i < 4; ++i)
                #pragma unroll
                for (int j = 0; j < 4; ++j)
                    acc[i][j] = fmaf(a[i], b[j], acc[i][j]);
        }
        __syncthreads();
    }
    #pragma unroll
    for (int i = 0; i < 4; ++i) {
        int r = r0 + ty * 4 + i;
        if (r < n)
            #pragma unroll
            for (int j = 0; j < 4; ++j)
                h[(size_t)r * 64 + tx * 4 + j] = acc[i][j];
    }
}

// Fused: pull-aggregate layer1 (64 ch) + bias + relu + (64->32) @ W2 -> h2.
__global__ __launch_bounds__(256) void k_layer1(const float* __restrict__ h1,
                                                const int2* __restrict__ pack,
                                                const int* __restrict__ rowst,
                                                const int* __restrict__ count,
                                                const float* __restrict__ dinv,
                                                const float* __restrict__ b1,
                                                const float* __restrict__ W2,
                                                float* __restrict__ h2, int n) {
    const int lane = threadIdx.x & 63;
    const int wid = (blockIdx.x * blockDim.x + threadIdx.x) >> 6;
    const int nwaves = (gridDim.x * blockDim.x) >> 6;
    const int half = lane >> 5, c = lane & 31;

    float w[32];
    #pragma unroll
    for (int k = 0; k < 32; ++k)
        w[k] = W2[(half * 32 + k) * 32 + c];
    const float bb = b1[lane];

    for (int v = wid; v < n; v += nwaves) {
        const float di = dinv[v];
        float acc = h1[v * 64 + lane] * di * di;   // self loop: norm = 1/deg
        const int start = rowst[v], cnt = count[v];
        const int2* pk = pack + start;
        int j = 0;
        for (; j + 4 <= cnt; j += 4) {
            int2 p0 = pk[j], p1 = pk[j + 1], p2 = pk[j + 2], p3 = pk[j + 3];
            float a0 = h1[p0.x * 64 + lane];
            float a1 = h1[p1.x * 64 + lane];
            float a2 = h1[p2.x * 64 + lane];
            float a3 = h1[p3.x * 64 + lane];
            acc = fmaf(a0, __int_as_float(p0.y), acc);
            acc = fmaf(a1, __int_as_float(p1.y), acc);
            acc = fmaf(a2, __int_as_float(p2.y), acc);
            acc = fmaf(a3, __int_as_float(p3.y), acc);
        }
        for (; j < cnt; ++j) {
            int2 p = pk[j];
            acc = fmaf(h1[p.x * 64 + lane], __int_as_float(p.y), acc);
        }
        const float r = fmaxf(acc + bb, 0.f);      // relu (leaky_relu = id on >=0)

        float o = 0.f;
        #pragma unroll
        for (int k = 0; k < 32; ++k)
            o = fmaf(__shfl(r, half * 32 + k, 64), w[k], o);
        o += __shfl_xor(o, 32, 64);
        if (half == 0) h2[v * 32 + c] = o;
    }
}

// Layer2 pull: out = pull(h2) + self + b2.
__global__ __launch_bounds__(256) void k_layer2(const float* __restrict__ h2,
                                                const int2* __restrict__ pack,
                                                const int* __restrict__ rowst,
                                                const int* __restrict__ count,
                                                const float* __restrict__ dinv,
                                                const float* __restrict__ b2,
                                                float* __restrict__ out, int n) {
    const int lane = threadIdx.x & 63;
    const int wid = (blockIdx.x * blockDim.x + threadIdx.x) >> 6;
    const int nwaves = (gridDim.x * blockDim.x) >> 6;
    const int half = lane >> 5, c = lane & 31;
    const float bb = b2[c];

    for (int v = wid; v < n; v += nwaves) {
        const float di = dinv[v];
        float acc = (half == 0) ? h2[v * 32 + c] * di * di : 0.f;
        const int start = rowst[v], cnt = count[v];
        const int2* pk = pack + start;
        int j = half;
        for (; j + 2 < cnt; j += 4) {
            int2 p0 = pk[j], p1 = pk[j + 2];
            float a0 = h2[p0.x * 32 + c];
            float a1 = h2[p1.x * 32 + c];
            acc = fmaf(a0, __int_as_float(p0.y), acc);
            acc = fmaf(a1, __int_as_float(p1.y), acc);
        }
        for (; j < cnt; j += 2) {
            int2 p = pk[j];
            acc = fmaf(h2[p.x * 32 + c], __int_as_float(p.y), acc);
        }
        acc += __shfl_xor(acc, 32, 64);
        if (half == 0) out[v * 32 + c] = acc + bb;
    }
}

extern "C" void kernel_launch(void* const* d_in, const int* in_sizes, int n_in,
                              void* d_out, int out_size, void* d_ws, size_t ws_size,
                              hipStream_t stream) {
    const float* x  = (const float*)d_in[0];   // [n,128]
    const int*   ei = (const int*)d_in[1];     // [2,E]
    const float* ew = (const float*)d_in[2];   // [E]
    const float* W1 = (const float*)d_in[3];   // [128,64]
    const float* b1 = (const float*)d_in[4];   // [64]
    const float* W2 = (const float*)d_in[5];   // [64,32]
    const float* b2 = (const float*)d_in[6];   // [32]
    float* out = (float*)d_out;

    const int n = in_sizes[0] / 128;
    const int E = in_sizes[2];
    const int* src = ei;
    const int* dst = ei + E;

    const int P = (n + SCAN_CHUNK - 1) / SCAN_CHUNK;   // scan blocks (98 for n=100k)

    // workspace: packed u64[n] | dinv f32[n] | count[n] | rowst[n] | cursor[n] |
    //            bsum[1024] | pack[E]int2 | h1[n*64] | h2[n*32]
    unsigned long long* packed = (unsigned long long*)d_ws;
    float* dinv   = (float*)(packed + n);
    int*   count  = (int*)(dinv + n);
    int*   rowst  = count + n;
    int*   cursor = rowst + n;
    int*   bsum   = cursor + n;
    int2*  pack   = (int2*)(bsum + 1024);
    float* h1     = (float*)(pack + E);
    float* h2     = h1 + (size_t)n * 64;

    hipMemsetAsync(packed, 0, (size_t)n * sizeof(unsigned long long), stream);
    k_hist<<<(E + 255) / 256, 256, 0, stream>>>(dst, ew, packed, E);
    k_dinv<<<(n + 255) / 256, 256, 0, stream>>>(packed, dinv, count, n);
    k_scan_a<<<P, 256, 0, stream>>>(count, bsum, n);
    k_scan_b<<<1, 1024, 0, stream>>>(bsum, P);
    k_scan_c<<<P, 256, 0, stream>>>(count, bsum, rowst, cursor, n);
    k_fill<<<(E + 255) / 256, 256, 0, stream>>>(src, dst, ew, dinv, cursor, pack, E);

    k_gemm1<<<(n + 63) / 64, 256, 0, stream>>>(x, W1, h1, n);
    k_layer1<<<2048, 256, 0, stream>>>(h1, pack, rowst, count, dinv, b1, W2, h2, n);
    k_layer2<<<2048, 256, 0, stream>>>(h2, pack, rowst, count, dinv, b2, out, n);
}

// Round 5
// 314.851 us; speedup vs baseline: 2.1141x; 1.1607x over previous
//
#include <hip/hip_runtime.h>
#include <hip/hip_bf16.h>

// GCN 2-layer, pull-based (CSR by dst, built on device each call).
// Round 5: latency-bound pull kernels -> float4 gather groups.
//   layer1: 16 lanes x float4 = one h1 row; wave gathers 4 edges per instr,
//           8 edges/iter with pack prefetch (2-stage pipeline).
//   layer2: 8 lanes x float4 = one h2 row; 8 edges per instr.

constexpr int SCAN_CHUNK = 1024;
constexpr unsigned long long CNT_ONE = 1ULL << 40;
constexpr unsigned long long W_MASK  = (1ULL << 40) - 1;

__device__ __forceinline__ float4 f4fma(float4 a, float s, float4 acc) {
    acc.x = fmaf(a.x, s, acc.x);
    acc.y = fmaf(a.y, s, acc.y);
    acc.z = fmaf(a.z, s, acc.z);
    acc.w = fmaf(a.w, s, acc.w);
    return acc;
}

__global__ __launch_bounds__(256) void k_hist(const int* __restrict__ dst,
                                              const float* __restrict__ w,
                                              unsigned long long* __restrict__ packed,
                                              int E) {
    int e = blockIdx.x * blockDim.x + threadIdx.x;
    if (e < E) {
        unsigned long long fixw = (unsigned long long)((double)w[e] * 4294967296.0);
        atomicAdd(&packed[dst[e]], CNT_ONE | fixw);
    }
}

__global__ __launch_bounds__(256) void k_dinv(const unsigned long long* __restrict__ packed,
                                              float* __restrict__ dinv,
                                              int* __restrict__ count, int n) {
    int i = blockIdx.x * blockDim.x + threadIdx.x;
    if (i < n) {
        unsigned long long p = packed[i];
        double d = (double)(p & W_MASK) * (1.0 / 4294967296.0) + 1.0;  // +1 self loop
        dinv[i] = rsqrtf((float)d);
        count[i] = (int)(p >> 40);
    }
}

__global__ __launch_bounds__(256) void k_scan_a(const int* __restrict__ count,
                                                int* __restrict__ bsum, int n) {
    __shared__ int wtot[4];
    const int t = threadIdx.x;
    const int base = blockIdx.x * SCAN_CHUNK + t * 4;
    int s = 0;
    #pragma unroll
    for (int k = 0; k < 4; ++k) {
        int i = base + k;
        if (i < n) s += count[i];
    }
    #pragma unroll
    for (int off = 1; off < 64; off <<= 1) s += __shfl_xor(s, off, 64);
    if ((t & 63) == 0) wtot[t >> 6] = s;
    __syncthreads();
    if (t == 0) bsum[blockIdx.x] = wtot[0] + wtot[1] + wtot[2] + wtot[3];
}

__global__ __launch_bounds__(1024) void k_scan_b(int* __restrict__ bsum, int P) {
    __shared__ int wtot[16];
    const int t = threadIdx.x;
    const int lane = t & 63, wv = t >> 6;
    int v = (t < P) ? bsum[t] : 0;
    int inc = v;
    #pragma unroll
    for (int off = 1; off < 64; off <<= 1) {
        int u = __shfl_up(inc, off, 64);
        if (lane >= off) inc += u;
    }
    if (lane == 63) wtot[wv] = inc;
    __syncthreads();
    int wbase = 0;
    for (int w = 0; w < wv; ++w) wbase += wtot[w];
    if (t < P) bsum[t] = wbase + inc - v;   // exclusive
}

__global__ __launch_bounds__(256) void k_scan_c(const int* __restrict__ count,
                                                const int* __restrict__ bsum,
                                                int* __restrict__ rowst,
                                                int* __restrict__ cursor, int n) {
    __shared__ int wtot[4];
    const int t = threadIdx.x;
    const int lane = t & 63, wv = t >> 6;
    const int base = blockIdx.x * SCAN_CHUNK + t * 4;
    int c[4];
    int s = 0;
    #pragma unroll
    for (int k = 0; k < 4; ++k) {
        int i = base + k;
        c[k] = (i < n) ? count[i] : 0;
        s += c[k];
    }
    int inc = s;
    #pragma unroll
    for (int off = 1; off < 64; off <<= 1) {
        int u = __shfl_up(inc, off, 64);
        if (lane >= off) inc += u;
    }
    if (lane == 63) wtot[wv] = inc;
    __syncthreads();
    int run = bsum[blockIdx.x] + (inc - s);
    for (int w = 0; w < wv; ++w) run += wtot[w];
    #pragma unroll
    for (int k = 0; k < 4; ++k) {
        int i = base + k;
        if (i < n) { rowst[i] = run; cursor[i] = run; }
        run += c[k];
    }
}

__global__ __launch_bounds__(256) void k_fill(const int* __restrict__ src,
                                              const int* __restrict__ dst,
                                              const float* __restrict__ w,
                                              const float* __restrict__ dinv,
                                              int* __restrict__ cursor,
                                              int2* __restrict__ pack, int E) {
    int e = blockIdx.x * blockDim.x + threadIdx.x;
    if (e < E) {
        int s = src[e], d = dst[e];
        float nm = dinv[s] * w[e] * dinv[d];
        int pos = atomicAdd(&cursor[d], 1);
        pack[pos] = make_int2(s, __float_as_int(nm));
    }
}

__global__ __launch_bounds__(256) void k_gemm1(const float* __restrict__ x,
                                               const float* __restrict__ W,
                                               float* __restrict__ h, int n) {
    constexpr int TM = 64, BK = 16;
    __shared__ float xs[BK][TM + 4];
    __shared__ float ws[BK][64 + 4];
    const int tid = threadIdx.x;
    const int tx = tid & 15, ty = tid >> 4;
    const int r0 = blockIdx.x * TM;

    float acc[4][4] = {};
    for (int k0 = 0; k0 < 128; k0 += BK) {
        {
            int kk = tid & 15;
            int row = tid >> 4;
            #pragma unroll
            for (int p = 0; p < 4; ++p) {
                int rr = row + p * 16;
                xs[kk][rr] = (r0 + rr < n) ? x[(size_t)(r0 + rr) * 128 + k0 + kk] : 0.f;
            }
        }
        {
            int c = tid & 63;
            int kb = tid >> 6;
            #pragma unroll
            for (int p = 0; p < 4; ++p) {
                int kk = kb + p * 4;
                ws[kk][c] = W[(size_t)(k0 + kk) * 64 + c];
            }
        }
        __syncthreads();
        #pragma unroll
        for (int kk = 0; kk < BK; ++kk) {
            const float4 av = *reinterpret_cast<const float4*>(&xs[kk][ty * 4]);
            const float4 bv = *reinterpret_cast<const float4*>(&ws[kk][tx * 4]);
            const float a[4] = {av.x, av.y, av.z, av.w};
            const float b[4] = {bv.x, bv.y, bv.z, bv.w};
            #pragma unroll
            for (int i = 0; i < 4; ++i)
                #pragma unroll
                for (int j = 0; j < 4; ++j)
                    acc[i][j] = fmaf(a[i], b[j], acc[i][j]);
        }
        __syncthreads();
    }
    #pragma unroll
    for (int i = 0; i < 4; ++i) {
        int r = r0 + ty * 4 + i;
        if (r < n)
            #pragma unroll
            for (int j = 0; j < 4; ++j)
                h[(size_t)r * 64 + tx * 4 + j] = acc[i][j];
    }
}

// Fused layer1: pull-aggregate (64 ch) + bias + relu + (64->32)@W2 -> h2.
// Lane layout: g = lane>>4 (edge group), q = lane&15 (channels 4q..4q+3).
// One gather instruction covers 4 edges; main loop 8 edges with pack prefetch.
__global__ __launch_bounds__(256) void k_layer1(const float* __restrict__ h1,
                                                const int2* __restrict__ pack,
                                                const int* __restrict__ rowst,
                                                const int* __restrict__ count,
                                                const float* __restrict__ dinv,
                                                const float* __restrict__ b1,
                                                const float* __restrict__ W2,
                                                float* __restrict__ h2, int n) {
    const int lane = threadIdx.x & 63;
    const int wid = (blockIdx.x * blockDim.x + threadIdx.x) >> 6;
    const int nwaves = (gridDim.x * blockDim.x) >> 6;
    const int g = lane >> 4;       // edge group 0..3
    const int q = lane & 15;       // float4 slot: channels 4q..4q+3
    const int half = lane >> 5, c = lane & 31;

    float w[32];
    #pragma unroll
    for (int m = 0; m < 32; ++m)
        w[m] = W2[(half * 32 + m) * 32 + c];
    const float4 bb = *reinterpret_cast<const float4*>(&b1[q * 4]);

    for (int v = wid; v < n; v += nwaves) {
        const float di = dinv[v];
        const float selfw = (g == 0) ? di * di : 0.f;
        float4 acc = make_float4(0.f, 0.f, 0.f, 0.f);
        acc = f4fma(*reinterpret_cast<const float4*>(&h1[(size_t)v * 64 + q * 4]),
                    selfw, acc);
        const int start = rowst[v], cnt = count[v];
        const int2* pk = pack + start;

        int j = 0;
        if (cnt >= 8) {
            int2 pa = pk[g];
            int2 pb = pk[4 + g];
            for (; j + 16 <= cnt; j += 8) {
                int2 na = pk[j + 8 + g];
                int2 nb = pk[j + 12 + g];
                float4 a = *reinterpret_cast<const float4*>(&h1[(size_t)pa.x * 64 + q * 4]);
                float4 b = *reinterpret_cast<const float4*>(&h1[(size_t)pb.x * 64 + q * 4]);
                acc = f4fma(a, __int_as_float(pa.y), acc);
                acc = f4fma(b, __int_as_float(pb.y), acc);
                pa = na; pb = nb;
            }
            {   // drain the in-flight block (edges j..j+7)
                float4 a = *reinterpret_cast<const float4*>(&h1[(size_t)pa.x * 64 + q * 4]);
                float4 b = *reinterpret_cast<const float4*>(&h1[(size_t)pb.x * 64 + q * 4]);
                acc = f4fma(a, __int_as_float(pa.y), acc);
                acc = f4fma(b, __int_as_float(pb.y), acc);
                j += 8;
            }
        }
        for (; j < cnt; j += 4) {   // predicated tail, <=2 iters
            int e = j + g;
            int2 p = (e < cnt) ? pk[e] : make_int2(v, 0);
            float4 a = *reinterpret_cast<const float4*>(&h1[(size_t)p.x * 64 + q * 4]);
            acc = f4fma(a, __int_as_float(p.y), acc);
        }

        // reduce across the 4 edge groups (lane bits 4,5)
        acc.x += __shfl_xor(acc.x, 16, 64); acc.y += __shfl_xor(acc.y, 16, 64);
        acc.z += __shfl_xor(acc.z, 16, 64); acc.w += __shfl_xor(acc.w, 16, 64);
        acc.x += __shfl_xor(acc.x, 32, 64); acc.y += __shfl_xor(acc.y, 32, 64);
        acc.z += __shfl_xor(acc.z, 32, 64); acc.w += __shfl_xor(acc.w, 32, 64);

        // bias + relu (leaky_relu = identity on >=0)
        const float r0_ = fmaxf(acc.x + bb.x, 0.f);
        const float r1_ = fmaxf(acc.y + bb.y, 0.f);
        const float r2_ = fmaxf(acc.z + bb.z, 0.f);
        const float r3_ = fmaxf(acc.w + bb.w, 0.f);

        // 64->32 projection: channel k=32*half+m lives in lane (k>>2), elem (k&3)
        float o = 0.f;
        #pragma unroll
        for (int m = 0; m < 32; ++m) {
            const int em = m & 3;
            float srcv = (em == 0) ? r0_ : (em == 1) ? r1_ : (em == 2) ? r2_ : r3_;
            float rv = __shfl(srcv, half * 8 + (m >> 2), 64);
            o = fmaf(rv, w[m], o);
        }
        o += __shfl_xor(o, 32, 64);
        if (half == 0) h2[(size_t)v * 32 + c] = o;
    }
}

// Layer2 pull: out = pull(h2) + self + b2.
// Lane layout: g = lane>>3 (8 edge groups), q = lane&7 (channels 4q..4q+3).
// One gather instruction covers 8 edges.
__global__ __launch_bounds__(256) void k_layer2(const float* __restrict__ h2,
                                                const int2* __restrict__ pack,
                                                const int* __restrict__ rowst,
                                                const int* __restrict__ count,
                                                const float* __restrict__ dinv,
                                                const float* __restrict__ b2,
                                                float* __restrict__ out, int n) {
    const int lane = threadIdx.x & 63;
    const int wid = (blockIdx.x * blockDim.x + threadIdx.x) >> 6;
    const int nwaves = (gridDim.x * blockDim.x) >> 6;
    const int g = lane >> 3;      // edge group 0..7
    const int q = lane & 7;       // float4 slot: channels 4q..4q+3
    const float4 bb = *reinterpret_cast<const float4*>(&b2[q * 4]);

    for (int v = wid; v < n; v += nwaves) {
        const float di = dinv[v];
        const float selfw = (g == 0) ? di * di : 0.f;
        float4 acc = make_float4(0.f, 0.f, 0.f, 0.f);
        acc = f4fma(*reinterpret_cast<const float4*>(&h2[(size_t)v * 32 + q * 4]),
                    selfw, acc);
        const int start = rowst[v], cnt = count[v];
        const int2* pk = pack + start;

        int j = 0;
        if (cnt >= 8) {
            int2 pa = pk[g];
            for (; j + 16 <= cnt; j += 8) {
                int2 na = pk[j + 8 + g];
                float4 a = *reinterpret_cast<const float4*>(&h2[(size_t)pa.x * 32 + q * 4]);
                acc = f4fma(a, __int_as_float(pa.y), acc);
                pa = na;
            }
            {
                float4 a = *reinterpret_cast<const float4*>(&h2[(size_t)pa.x * 32 + q * 4]);
                acc = f4fma(a, __int_as_float(pa.y), acc);
                j += 8;
            }
        }
        for (; j < cnt; j += 8) {   // predicated tail, <=2 iters
            int e = j + g;
            int2 p = (e < cnt) ? pk[e] : make_int2(v, 0);
            float4 a = *reinterpret_cast<const float4*>(&h2[(size_t)p.x * 32 + q * 4]);
            acc = f4fma(a, __int_as_float(p.y), acc);
        }

        // reduce across 8 edge groups (lane bits 3,4,5)
        acc.x += __shfl_xor(acc.x, 8, 64);  acc.y += __shfl_xor(acc.y, 8, 64);
        acc.z += __shfl_xor(acc.z, 8, 64);  acc.w += __shfl_xor(acc.w, 8, 64);
        acc.x += __shfl_xor(acc.x, 16, 64); acc.y += __shfl_xor(acc.y, 16, 64);
        acc.z += __shfl_xor(acc.z, 16, 64); acc.w += __shfl_xor(acc.w, 16, 64);
        acc.x += __shfl_xor(acc.x, 32, 64); acc.y += __shfl_xor(acc.y, 32, 64);
        acc.z += __shfl_xor(acc.z, 32, 64); acc.w += __shfl_xor(acc.w, 32, 64);

        if (g == 0) {
            float4 r = make_float4(acc.x + bb.x, acc.y + bb.y,
                                   acc.z + bb.z, acc.w + bb.w);
            *reinterpret_cast<float4*>(&out[(size_t)v * 32 + q * 4]) = r;
        }
    }
}

extern "C" void kernel_launch(void* const* d_in, const int* in_sizes, int n_in,
                              void* d_out, int out_size, void* d_ws, size_t ws_size,
                              hipStream_t stream) {
    const float* x  = (const float*)d_in[0];   // [n,128]
    const int*   ei = (const int*)d_in[1];     // [2,E]
    const float* ew = (const float*)d_in[2];   // [E]
    const float* W1 = (const float*)d_in[3];   // [128,64]
    const float* b1 = (const float*)d_in[4];   // [64]
    const float* W2 = (const float*)d_in[5];   // [64,32]
    const float* b2 = (const float*)d_in[6];   // [32]
    float* out = (float*)d_out;

    const int n = in_sizes[0] / 128;
    const int E = in_sizes[2];
    const int* src = ei;
    const int* dst = ei + E;

    const int P = (n + SCAN_CHUNK - 1) / SCAN_CHUNK;

    // workspace: packed u64[n] | dinv f32[n] | count[n] | rowst[n] | cursor[n] |
    //            bsum[1024] | pack[E]int2 | h1[n*64] | h2[n*32]
    unsigned long long* packed = (unsigned long long*)d_ws;
    float* dinv   = (float*)(packed + n);
    int*   count  = (int*)(dinv + n);
    int*   rowst  = count + n;
    int*   cursor = rowst + n;
    int*   bsum   = cursor + n;
    int2*  pack   = (int2*)(bsum + 1024);
    float* h1     = (float*)(pack + E);
    float* h2     = h1 + (size_t)n * 64;

    hipMemsetAsync(packed, 0, (size_t)n * sizeof(unsigned long long), stream);
    k_hist<<<(E + 255) / 256, 256, 0, stream>>>(dst, ew, packed, E);
    k_dinv<<<(n + 255) / 256, 256, 0, stream>>>(packed, dinv, count, n);
    k_scan_a<<<P, 256, 0, stream>>>(count, bsum, n);
    k_scan_b<<<1, 1024, 0, stream>>>(bsum, P);
    k_scan_c<<<P, 256, 0, stream>>>(count, bsum, rowst, cursor, n);
    k_fill<<<(E + 255) / 256, 256, 0, stream>>>(src, dst, ew, dinv, cursor, pack, E);

    k_gemm1<<<(n + 63) / 64, 256, 0, stream>>>(x, W1, h1, n);
    k_layer1<<<2048, 256, 0, stream>>>(h1, pack, rowst, count, dinv, b1, W2, h2, n);
    k_layer2<<<2048, 256, 0, stream>>>(h2, pack, rowst, count, dinv, b2, out, n);
}

// Round 6
// 308.053 us; speedup vs baseline: 2.1607x; 1.0221x over previous
//
#include <hip/hip_runtime.h>
#include <hip/hip_bf16.h>

// GCN 2-layer, pull-based (CSR by dst, built on device each call).
// Round 6: h1 stored as bf16 (RNE). Layer1's per-XCD compulsory fetch was
// 8 XCD x 25.6 MB = 195 MB at ~2.3 TB/s (random-sector ceiling); halving
// the array halves the fetch. h2/layer2 stay fp32 (precision isolation).

constexpr int SCAN_CHUNK = 1024;
constexpr unsigned long long CNT_ONE = 1ULL << 40;
constexpr unsigned long long W_MASK  = (1ULL << 40) - 1;

__device__ __forceinline__ float4 f4fma(float4 a, float s, float4 acc) {
    acc.x = fmaf(a.x, s, acc.x);
    acc.y = fmaf(a.y, s, acc.y);
    acc.z = fmaf(a.z, s, acc.z);
    acc.w = fmaf(a.w, s, acc.w);
    return acc;
}

__device__ __forceinline__ unsigned short f2bf_rne(float f) {
    unsigned u = __float_as_uint(f);
    unsigned r = (u + 0x7FFFu + ((u >> 16) & 1u)) >> 16;
    return (unsigned short)r;
}

__device__ __forceinline__ float4 bf4_to_f4(ushort4 u) {
    return make_float4(__uint_as_float((unsigned)u.x << 16),
                       __uint_as_float((unsigned)u.y << 16),
                       __uint_as_float((unsigned)u.z << 16),
                       __uint_as_float((unsigned)u.w << 16));
}

__global__ __launch_bounds__(256) void k_hist(const int* __restrict__ dst,
                                              const float* __restrict__ w,
                                              unsigned long long* __restrict__ packed,
                                              int E) {
    int e = blockIdx.x * blockDim.x + threadIdx.x;
    if (e < E) {
        unsigned long long fixw = (unsigned long long)((double)w[e] * 4294967296.0);
        atomicAdd(&packed[dst[e]], CNT_ONE | fixw);
    }
}

__global__ __launch_bounds__(256) void k_dinv(const unsigned long long* __restrict__ packed,
                                              float* __restrict__ dinv,
                                              int* __restrict__ count, int n) {
    int i = blockIdx.x * blockDim.x + threadIdx.x;
    if (i < n) {
        unsigned long long p = packed[i];
        double d = (double)(p & W_MASK) * (1.0 / 4294967296.0) + 1.0;  // +1 self loop
        dinv[i] = rsqrtf((float)d);
        count[i] = (int)(p >> 40);
    }
}

__global__ __launch_bounds__(256) void k_scan_a(const int* __restrict__ count,
                                                int* __restrict__ bsum, int n) {
    __shared__ int wtot[4];
    const int t = threadIdx.x;
    const int base = blockIdx.x * SCAN_CHUNK + t * 4;
    int s = 0;
    #pragma unroll
    for (int k = 0; k < 4; ++k) {
        int i = base + k;
        if (i < n) s += count[i];
    }
    #pragma unroll
    for (int off = 1; off < 64; off <<= 1) s += __shfl_xor(s, off, 64);
    if ((t & 63) == 0) wtot[t >> 6] = s;
    __syncthreads();
    if (t == 0) bsum[blockIdx.x] = wtot[0] + wtot[1] + wtot[2] + wtot[3];
}

__global__ __launch_bounds__(1024) void k_scan_b(int* __restrict__ bsum, int P) {
    __shared__ int wtot[16];
    const int t = threadIdx.x;
    const int lane = t & 63, wv = t >> 6;
    int v = (t < P) ? bsum[t] : 0;
    int inc = v;
    #pragma unroll
    for (int off = 1; off < 64; off <<= 1) {
        int u = __shfl_up(inc, off, 64);
        if (lane >= off) inc += u;
    }
    if (lane == 63) wtot[wv] = inc;
    __syncthreads();
    int wbase = 0;
    for (int w = 0; w < wv; ++w) wbase += wtot[w];
    if (t < P) bsum[t] = wbase + inc - v;   // exclusive
}

__global__ __launch_bounds__(256) void k_scan_c(const int* __restrict__ count,
                                                const int* __restrict__ bsum,
                                                int* __restrict__ rowst,
                                                int* __restrict__ cursor, int n) {
    __shared__ int wtot[4];
    const int t = threadIdx.x;
    const int lane = t & 63, wv = t >> 6;
    const int base = blockIdx.x * SCAN_CHUNK + t * 4;
    int c[4];
    int s = 0;
    #pragma unroll
    for (int k = 0; k < 4; ++k) {
        int i = base + k;
        c[k] = (i < n) ? count[i] : 0;
        s += c[k];
    }
    int inc = s;
    #pragma unroll
    for (int off = 1; off < 64; off <<= 1) {
        int u = __shfl_up(inc, off, 64);
        if (lane >= off) inc += u;
    }
    if (lane == 63) wtot[wv] = inc;
    __syncthreads();
    int run = bsum[blockIdx.x] + (inc - s);
    for (int w = 0; w < wv; ++w) run += wtot[w];
    #pragma unroll
    for (int k = 0; k < 4; ++k) {
        int i = base + k;
        if (i < n) { rowst[i] = run; cursor[i] = run; }
        run += c[k];
    }
}

__global__ __launch_bounds__(256) void k_fill(const int* __restrict__ src,
                                              const int* __restrict__ dst,
                                              const float* __restrict__ w,
                                              const float* __restrict__ dinv,
                                              int* __restrict__ cursor,
                                              int2* __restrict__ pack, int E) {
    int e = blockIdx.x * blockDim.x + threadIdx.x;
    if (e < E) {
        int s = src[e], d = dst[e];
        float nm = dinv[s] * w[e] * dinv[d];
        int pos = atomicAdd(&cursor[d], 1);
        pack[pos] = make_int2(s, __float_as_int(nm));
    }
}

// GEMM1: h1 = bf16(x @ W1)  (n x 128 @ 128 x 64). 64x64 tile, 4x4/thread.
__global__ __launch_bounds__(256) void k_gemm1(const float* __restrict__ x,
                                               const float* __restrict__ W,
                                               unsigned short* __restrict__ h, int n) {
    constexpr int TM = 64, BK = 16;
    __shared__ float xs[BK][TM + 4];
    __shared__ float ws[BK][64 + 4];
    const int tid = threadIdx.x;
    const int tx = tid & 15, ty = tid >> 4;
    const int r0 = blockIdx.x * TM;

    float acc[4][4] = {};
    for (int k0 = 0; k0 < 128; k0 += BK) {
        {
            int kk = tid & 15;
            int row = tid >> 4;
            #pragma unroll
            for (int p = 0; p < 4; ++p) {
                int rr = row + p * 16;
                xs[kk][rr] = (r0 + rr < n) ? x[(size_t)(r0 + rr) * 128 + k0 + kk] : 0.f;
            }
        }
        {
            int c = tid & 63;
            int kb = tid >> 6;
            #pragma unroll
            for (int p = 0; p < 4; ++p) {
                int kk = kb + p * 4;
                ws[kk][c] = W[(size_t)(k0 + kk) * 64 + c];
            }
        }
        __syncthreads();
        #pragma unroll
        for (int kk = 0; kk < BK; ++kk) {
            const float4 av = *reinterpret_cast<const float4*>(&xs[kk][ty * 4]);
            const float4 bv = *reinterpret_cast<const float4*>(&ws[kk][tx * 4]);
            const float a[4] = {av.x, av.y, av.z, av.w};
            const float b[4] = {bv.x, bv.y, bv.z, bv.w};
            #pragma unroll
            for (int i = 0; i < 4; ++i)
                #pragma unroll
                for (int j = 0; j < 4; ++j)
                    acc[i][j] = fmaf(a[i], b[j], acc[i][j]);
        }
        __syncthreads();
    }
    #pragma unroll
    for (int i = 0; i < 4; ++i) {
        int r = r0 + ty * 4 + i;
        if (r < n) {
            ushort4 o;
            o.x = f2bf_rne(acc[i][0]);
            o.y = f2bf_rne(acc[i][1]);
            o.z = f2bf_rne(acc[i][2]);
            o.w = f2bf_rne(acc[i][3]);
            *reinterpret_cast<ushort4*>(&h[(size_t)r * 64 + tx * 4]) = o;
        }
    }
}

// Fused layer1: pull-aggregate bf16 h1 (64 ch) + bias + relu + (64->32)@W2 -> h2 (fp32).
// Lane layout: g = lane>>4 (edge group 0..3), q = lane&15 (channels 4q..4q+3).
// One 8B gather instruction covers 4 edges; 8 edges/iter with pack prefetch.
__global__ __launch_bounds__(256) void k_layer1(const unsigned short* __restrict__ h1,
                                                const int2* __restrict__ pack,
                                                const int* __restrict__ rowst,
                                                const int* __restrict__ count,
                                                const float* __restrict__ dinv,
                                                const float* __restrict__ b1,
                                                const float* __restrict__ W2,
                                                float* __restrict__ h2, int n) {
    const int lane = threadIdx.x & 63;
    const int wid = (blockIdx.x * blockDim.x + threadIdx.x) >> 6;
    const int nwaves = (gridDim.x * blockDim.x) >> 6;
    const int g = lane >> 4;       // edge group 0..3
    const int q = lane & 15;       // channels 4q..4q+3
    const int half = lane >> 5, c = lane & 31;

    float w[32];
    #pragma unroll
    for (int m = 0; m < 32; ++m)
        w[m] = W2[(half * 32 + m) * 32 + c];
    const float4 bb = *reinterpret_cast<const float4*>(&b1[q * 4]);

    for (int v = wid; v < n; v += nwaves) {
        const float di = dinv[v];
        const float selfw = (g == 0) ? di * di : 0.f;
        float4 acc = make_float4(0.f, 0.f, 0.f, 0.f);
        acc = f4fma(bf4_to_f4(*reinterpret_cast<const ushort4*>(&h1[(size_t)v * 64 + q * 4])),
                    selfw, acc);
        const int start = rowst[v], cnt = count[v];
        const int2* pk = pack + start;

        int j = 0;
        if (cnt >= 8) {
            int2 pa = pk[g];
            int2 pb = pk[4 + g];
            for (; j + 16 <= cnt; j += 8) {
                int2 na = pk[j + 8 + g];
                int2 nb = pk[j + 12 + g];
                float4 a = bf4_to_f4(*reinterpret_cast<const ushort4*>(&h1[(size_t)pa.x * 64 + q * 4]));
                float4 b = bf4_to_f4(*reinterpret_cast<const ushort4*>(&h1[(size_t)pb.x * 64 + q * 4]));
                acc = f4fma(a, __int_as_float(pa.y), acc);
                acc = f4fma(b, __int_as_float(pb.y), acc);
                pa = na; pb = nb;
            }
            {   // drain in-flight block (edges j..j+7)
                float4 a = bf4_to_f4(*reinterpret_cast<const ushort4*>(&h1[(size_t)pa.x * 64 + q * 4]));
                float4 b = bf4_to_f4(*reinterpret_cast<const ushort4*>(&h1[(size_t)pb.x * 64 + q * 4]));
                acc = f4fma(a, __int_as_float(pa.y), acc);
                acc = f4fma(b, __int_as_float(pb.y), acc);
                j += 8;
            }
        }
        for (; j < cnt; j += 4) {   // predicated tail, <=2 iters
            int e = j + g;
            int2 p = (e < cnt) ? pk[e] : make_int2(v, 0);
            float4 a = bf4_to_f4(*reinterpret_cast<const ushort4*>(&h1[(size_t)p.x * 64 + q * 4]));
            acc = f4fma(a, __int_as_float(p.y), acc);
        }

        // reduce across the 4 edge groups (lane bits 4,5)
        acc.x += __shfl_xor(acc.x, 16, 64); acc.y += __shfl_xor(acc.y, 16, 64);
        acc.z += __shfl_xor(acc.z, 16, 64); acc.w += __shfl_xor(acc.w, 16, 64);
        acc.x += __shfl_xor(acc.x, 32, 64); acc.y += __shfl_xor(acc.y, 32, 64);
        acc.z += __shfl_xor(acc.z, 32, 64); acc.w += __shfl_xor(acc.w, 32, 64);

        // bias + relu (leaky_relu = identity on >=0)
        const float r0_ = fmaxf(acc.x + bb.x, 0.f);
        const float r1_ = fmaxf(acc.y + bb.y, 0.f);
        const float r2_ = fmaxf(acc.z + bb.z, 0.f);
        const float r3_ = fmaxf(acc.w + bb.w, 0.f);

        // 64->32 projection: channel k=32*half+m lives in lane (k>>2), elem (k&3)
        float o = 0.f;
        #pragma unroll
        for (int m = 0; m < 32; ++m) {
            const int em = m & 3;
            float srcv = (em == 0) ? r0_ : (em == 1) ? r1_ : (em == 2) ? r2_ : r3_;
            float rv = __shfl(srcv, half * 8 + (m >> 2), 64);
            o = fmaf(rv, w[m], o);
        }
        o += __shfl_xor(o, 32, 64);
        if (half == 0) h2[(size_t)v * 32 + c] = o;
    }
}

// Layer2 pull: out = pull(h2 fp32) + self + b2.
// Lane layout: g = lane>>3 (8 edge groups), q = lane&7 (channels 4q..4q+3).
__global__ __launch_bounds__(256) void k_layer2(const float* __restrict__ h2,
                                                const int2* __restrict__ pack,
                                                const int* __restrict__ rowst,
                                                const int* __restrict__ count,
                                                const float* __restrict__ dinv,
                                                const float* __restrict__ b2,
                                                float* __restrict__ out, int n) {
    const int lane = threadIdx.x & 63;
    const int wid = (blockIdx.x * blockDim.x + threadIdx.x) >> 6;
    const int nwaves = (gridDim.x * blockDim.x) >> 6;
    const int g = lane >> 3;      // edge group 0..7
    const int q = lane & 7;       // channels 4q..4q+3
    const float4 bb = *reinterpret_cast<const float4*>(&b2[q * 4]);

    for (int v = wid; v < n; v += nwaves) {
        const float di = dinv[v];
        const float selfw = (g == 0) ? di * di : 0.f;
        float4 acc = make_float4(0.f, 0.f, 0.f, 0.f);
        acc = f4fma(*reinterpret_cast<const float4*>(&h2[(size_t)v * 32 + q * 4]),
                    selfw, acc);
        const int start = rowst[v], cnt = count[v];
        const int2* pk = pack + start;

        int j = 0;
        if (cnt >= 8) {
            int2 pa = pk[g];
            for (; j + 16 <= cnt; j += 8) {
                int2 na = pk[j + 8 + g];
                float4 a = *reinterpret_cast<const float4*>(&h2[(size_t)pa.x * 32 + q * 4]);
                acc = f4fma(a, __int_as_float(pa.y), acc);
                pa = na;
            }
            {
                float4 a = *reinterpret_cast<const float4*>(&h2[(size_t)pa.x * 32 + q * 4]);
                acc = f4fma(a, __int_as_float(pa.y), acc);
                j += 8;
            }
        }
        for (; j < cnt; j += 8) {   // predicated tail, <=2 iters
            int e = j + g;
            int2 p = (e < cnt) ? pk[e] : make_int2(v, 0);
            float4 a = *reinterpret_cast<const float4*>(&h2[(size_t)p.x * 32 + q * 4]);
            acc = f4fma(a, __int_as_float(p.y), acc);
        }

        // reduce across 8 edge groups (lane bits 3,4,5)
        acc.x += __shfl_xor(acc.x, 8, 64);  acc.y += __shfl_xor(acc.y, 8, 64);
        acc.z += __shfl_xor(acc.z, 8, 64);  acc.w += __shfl_xor(acc.w, 8, 64);
        acc.x += __shfl_xor(acc.x, 16, 64); acc.y += __shfl_xor(acc.y, 16, 64);
        acc.z += __shfl_xor(acc.z, 16, 64); acc.w += __shfl_xor(acc.w, 16, 64);
        acc.x += __shfl_xor(acc.x, 32, 64); acc.y += __shfl_xor(acc.y, 32, 64);
        acc.z += __shfl_xor(acc.z, 32, 64); acc.w += __shfl_xor(acc.w, 32, 64);

        if (g == 0) {
            float4 r = make_float4(acc.x + bb.x, acc.y + bb.y,
                                   acc.z + bb.z, acc.w + bb.w);
            *reinterpret_cast<float4*>(&out[(size_t)v * 32 + q * 4]) = r;
        }
    }
}

extern "C" void kernel_launch(void* const* d_in, const int* in_sizes, int n_in,
                              void* d_out, int out_size, void* d_ws, size_t ws_size,
                              hipStream_t stream) {
    const float* x  = (const float*)d_in[0];   // [n,128]
    const int*   ei = (const int*)d_in[1];     // [2,E]
    const float* ew = (const float*)d_in[2];   // [E]
    const float* W1 = (const float*)d_in[3];   // [128,64]
    const float* b1 = (const float*)d_in[4];   // [64]
    const float* W2 = (const float*)d_in[5];   // [64,32]
    const float* b2 = (const float*)d_in[6];   // [32]
    float* out = (float*)d_out;

    const int n = in_sizes[0] / 128;
    const int E = in_sizes[2];
    const int* src = ei;
    const int* dst = ei + E;

    const int P = (n + SCAN_CHUNK - 1) / SCAN_CHUNK;

    // workspace: packed u64[n] | dinv f32[n] | count[n] | rowst[n] | cursor[n] |
    //            bsum[1024] | pack[E]int2 | h1 bf16[n*64] | h2 f32[n*32]
    unsigned long long* packed = (unsigned long long*)d_ws;
    float* dinv   = (float*)(packed + n);
    int*   count  = (int*)(dinv + n);
    int*   rowst  = count + n;
    int*   cursor = rowst + n;
    int*   bsum   = cursor + n;
    int2*  pack   = (int2*)(bsum + 1024);
    unsigned short* h1 = (unsigned short*)(pack + E);
    float* h2     = (float*)(h1 + (size_t)n * 64);

    hipMemsetAsync(packed, 0, (size_t)n * sizeof(unsigned long long), stream);
    k_hist<<<(E + 255) / 256, 256, 0, stream>>>(dst, ew, packed, E);
    k_dinv<<<(n + 255) / 256, 256, 0, stream>>>(packed, dinv, count, n);
    k_scan_a<<<P, 256, 0, stream>>>(count, bsum, n);
    k_scan_b<<<1, 1024, 0, stream>>>(bsum, P);
    k_scan_c<<<P, 256, 0, stream>>>(count, bsum, rowst, cursor, n);
    k_fill<<<(E + 255) / 256, 256, 0, stream>>>(src, dst, ew, dinv, cursor, pack, E);

    k_gemm1<<<(n + 63) / 64, 256, 0, stream>>>(x, W1, h1, n);
    k_layer1<<<2048, 256, 0, stream>>>(h1, pack, rowst, count, dinv, b1, W2, h2, n);
    k_layer2<<<2048, 256, 0, stream>>>(h2, pack, rowst, count, dinv, b2, out, n);
}